// Round 1
// baseline (248.711 us; speedup 1.0000x reference)
//
#include <hip/hip_runtime.h>

// Problem constants (match reference)
#define NPROP 4096
#define NTOK  16777216

// ws layout: [0, NPROP) int counts | [NPROP, 2*NPROP) float sums | [2*NPROP] float total
// out layout: out[0]=stratified_loss, out[1]=unweighted_loss, out[2..2+NPROP)=new_freq

__global__ void zero_ws_kernel(int* __restrict__ g_cnt, float* __restrict__ g_sum,
                               float* __restrict__ g_total) {
    int i = blockIdx.x * blockDim.x + threadIdx.x;
    if (i < NPROP) {
        g_cnt[i] = 0;
        g_sum[i] = 0.0f;
    }
    if (i == 0) g_total[0] = 0.0f;
}

__global__ __launch_bounds__(1024) void hist_kernel(
    const int* __restrict__ ids, const float* __restrict__ losses,
    int* __restrict__ g_cnt, float* __restrict__ g_sum, float* __restrict__ g_total) {
    __shared__ int   s_cnt[NPROP];
    __shared__ float s_sum[NPROP];

    for (int i = threadIdx.x; i < NPROP; i += blockDim.x) {
        s_cnt[i] = 0;
        s_sum[i] = 0.0f;
    }
    __syncthreads();

    const int4*   ids4 = (const int4*)ids;
    const float4* ls4  = (const float4*)losses;
    const int n4 = NTOK >> 2;

    int tid    = blockIdx.x * blockDim.x + threadIdx.x;
    int stride = gridDim.x * blockDim.x;

    float local_total = 0.0f;
    for (int i = tid; i < n4; i += stride) {
        int4   id = ids4[i];
        float4 l  = ls4[i];
        atomicAdd(&s_cnt[id.x], 1);
        atomicAdd(&s_sum[id.x], l.x);
        atomicAdd(&s_cnt[id.y], 1);
        atomicAdd(&s_sum[id.y], l.y);
        atomicAdd(&s_cnt[id.z], 1);
        atomicAdd(&s_sum[id.z], l.z);
        atomicAdd(&s_cnt[id.w], 1);
        atomicAdd(&s_sum[id.w], l.w);
        local_total += (l.x + l.y) + (l.z + l.w);
    }

    // wave64 reduce local_total, one global atomic per wave
    for (int off = 32; off > 0; off >>= 1)
        local_total += __shfl_down(local_total, off, 64);
    if ((threadIdx.x & 63) == 0)
        atomicAdd(g_total, local_total);

    __syncthreads();
    // flush per-block histogram (coalesced: consecutive lanes -> consecutive bins)
    for (int i = threadIdx.x; i < NPROP; i += blockDim.x) {
        int c = s_cnt[i];
        if (c != 0) {
            atomicAdd(&g_cnt[i], c);
            atomicAdd(&g_sum[i], s_sum[i]);
        }
    }
}

__global__ __launch_bounds__(1024) void finalize_kernel(
    const int* __restrict__ g_cnt, const float* __restrict__ g_sum,
    const float* __restrict__ g_total, const float* __restrict__ prop_freq,
    const int* __restrict__ d_bc, float* __restrict__ out) {
    const int bc_i = d_bc[0];
    const float bc = (float)bc_i;

    float s_raw = 0.0f;   // sum of weights (pre-normalization)
    float s_dot = 0.0f;   // sum of mean_loss * weight

    // ramp factors (uniform across properties)
    float ramp = fminf(1.0f, (bc - 1000.0f) / 200.0f);
    float frac = bc / 3000.0f;

    for (int p = threadIdx.x; p < NPROP; p += blockDim.x) {
        float cnt = (float)g_cnt[p];
        bool present = cnt > 0.0f;
        float mean_loss = present ? g_sum[p] / fmaxf(cnt, 1.0f) : 0.0f;

        float batch_freq = cnt / ((float)NTOK + 1e-6f);
        float new_freq = prop_freq[p] * 0.99f + (present ? 0.01f * batch_freq : 0.0f);
        out[2 + p] = new_freq;

        float freq_cl = fmaxf(new_freq, 1e-5f);
        float raw = 1.0f / sqrtf(freq_cl + 1e-6f);
        raw = 1.0f + ramp * (raw - 1.0f);
        raw = fminf(30.0f, raw);
        if (bc_i <= 3000) raw = raw * frac + (1.0f - frac);
        if (bc_i <= 1000) raw = 1.0f;

        float w = present ? raw : 0.0f;
        s_raw += w;
        s_dot += mean_loss * w;
    }

    // block reduction (1024 threads = 16 waves)
    for (int off = 32; off > 0; off >>= 1) {
        s_raw += __shfl_down(s_raw, off, 64);
        s_dot += __shfl_down(s_dot, off, 64);
    }
    __shared__ float r_raw[16];
    __shared__ float r_dot[16];
    int wave = threadIdx.x >> 6;
    if ((threadIdx.x & 63) == 0) {
        r_raw[wave] = s_raw;
        r_dot[wave] = s_dot;
    }
    __syncthreads();
    if (threadIdx.x == 0) {
        float t_raw = 0.0f, t_dot = 0.0f;
        int nwaves = blockDim.x >> 6;
        for (int i = 0; i < nwaves; ++i) {
            t_raw += r_raw[i];
            t_dot += r_dot[i];
        }
        out[0] = t_dot / (t_raw + 1e-6f);               // stratified_loss
        out[1] = g_total[0] / (float)NTOK;              // unweighted_loss
    }
}

extern "C" void kernel_launch(void* const* d_in, const int* in_sizes, int n_in,
                              void* d_out, int out_size, void* d_ws, size_t ws_size,
                              hipStream_t stream) {
    const int*   ids       = (const int*)d_in[0];
    const float* losses    = (const float*)d_in[1];
    const float* prop_freq = (const float*)d_in[2];
    const int*   d_bc      = (const int*)d_in[3];
    float* out = (float*)d_out;

    int*   g_cnt   = (int*)d_ws;
    float* g_sum   = (float*)d_ws + NPROP;
    float* g_total = (float*)d_ws + 2 * NPROP;

    zero_ws_kernel<<<NPROP / 256, 256, 0, stream>>>(g_cnt, g_sum, g_total);

    // 512 blocks x 1024 threads: 32 KB LDS/block -> 2 blocks/CU, 32 waves/CU
    hist_kernel<<<512, 1024, 0, stream>>>(ids, losses, g_cnt, g_sum, g_total);

    finalize_kernel<<<1, 1024, 0, stream>>>(g_cnt, g_sum, g_total, prop_freq, d_bc, out);
}